// Round 11
// baseline (80.638 us; speedup 1.0000x reference)
//
#include <hip/hip_runtime.h>
#include <stdint.h>

#define NN 4096
#define DD 256
#define TH 0.04f

typedef __attribute__((ext_vector_type(4))) float f32x4;
typedef __attribute__((ext_vector_type(16))) float f32x16;
typedef __attribute__((ext_vector_type(8))) short s16x8;
typedef unsigned short us;

__device__ __forceinline__ us f2bf(float f) {
  union { float f; uint32_t u; } x; x.f = f;
  uint32_t u = x.u;
  return (us)((u + 0x7FFFu + ((u >> 16) & 1u)) >> 16);  // RNE
}
__device__ __forceinline__ float bf2f(us h) {
  union { uint32_t u; float f; } x; x.u = ((uint32_t)h) << 16;
  return x.f;
}

// ======== hw (self-staged W): P1 = feat@W1 -> hWb1 [u][d] bf16 + 16x16x32
// B-frag panels hWbP1[dt16(16)][ks32(128)][512]. 16 u-rows/block, 256 thr.
__device__ __forceinline__ void hw_selfstage(const float* __restrict__ H,
                                             const float* __restrict__ W,
                                             int u0,
                                             us* __restrict__ hWb,
                                             us* __restrict__ hWbP,
                                             char* smem) {
  us (*hs)[264] = reinterpret_cast<us(*)[264]>(smem);
  us (*wt)[34]  = reinterpret_cast<us(*)[34]>(smem + 16 * 264 * 2);
  us (*lt)[260] = reinterpret_cast<us(*)[260]>(smem + 16 * 264 * 2 + 256 * 34 * 2);
  const int t = threadIdx.x;
#pragma unroll
  for (int rep = 0; rep < 4; ++rep) {
    const int flat = rep * 256 + t;
    const int row = flat >> 6, c4 = (flat & 63) * 4;
    f32x4 v = *reinterpret_cast<const f32x4*>(H + (size_t)(u0 + row) * DD + c4);
    uint2 pw;
    pw.x = (uint32_t)f2bf(v[0]) | ((uint32_t)f2bf(v[1]) << 16);
    pw.y = (uint32_t)f2bf(v[2]) | ((uint32_t)f2bf(v[3]) << 16);
    *reinterpret_cast<uint2*>(&hs[row][c4]) = pw;
  }
  const int lane = t & 63, w = t >> 6, l15 = lane & 15, l4 = lane >> 4;
  const f32x4 z = {0.f, 0.f, 0.f, 0.f};
  f32x4 acc[4];
#pragma unroll
  for (int jn = 0; jn < 4; ++jn) acc[jn] = z;
#pragma unroll 1
  for (int ks = 0; ks < 8; ++ks) {
    __syncthreads();
#pragma unroll
    for (int rr = 0; rr < 8; ++rr) {
      const int flat = rr * 256 + t;
      const int k = flat >> 6, d0 = (flat & 63) * 4;
      f32x4 wv = *reinterpret_cast<const f32x4*>(W + (size_t)(ks * 32 + k) * DD + d0);
      wt[d0 + 0][k] = f2bf(wv[0]);
      wt[d0 + 1][k] = f2bf(wv[1]);
      wt[d0 + 2][k] = f2bf(wv[2]);
      wt[d0 + 3][k] = f2bf(wv[3]);
    }
    __syncthreads();
    s16x8 af = *reinterpret_cast<const s16x8*>(&hs[l15][ks * 32 + l4 * 8]);
#pragma unroll
    for (int jn = 0; jn < 4; ++jn) {
      const int dt = w * 4 + jn;
      s16x8 bf = *reinterpret_cast<const s16x8*>(&wt[dt * 16 + l15][l4 * 8]);
      acc[jn] = __builtin_amdgcn_mfma_f32_16x16x32_bf16(af, bf, acc[jn], 0, 0, 0);
    }
  }
#pragma unroll
  for (int jn = 0; jn < 4; ++jn) {
    const int d = w * 64 + jn * 16 + l15;
#pragma unroll
    for (int r = 0; r < 4; ++r) {
      const int ul = l4 * 4 + r;              // C/D 16x16: row=l4*4+r, col=l15
      us hv = f2bf(acc[jn][r]);
      hWb[(size_t)(u0 + ul) * DD + d] = hv;
      lt[ul][d] = hv;
    }
  }
  __syncthreads();
  // panel write in 16x16x32 B-frag layout: frag (f=dt16, ks=u0>>5), this block
  // fills lane-half `half`: elem (lane l, j): u = ks*32+(l>>4)*8+j, d = f*16+(l&15)
  const int ks2 = u0 >> 5, half = (u0 >> 4) & 1;
#pragma unroll
  for (int e = 0; e < 2; ++e) {
    const int s = t * 2 + e;
    const int f = s >> 5, lrel = s & 31;
    const int l = half * 32 + lrel;
    const int ub = (lrel >> 4) * 8;
    const int d = f * 16 + (lrel & 15);
    uint4 val;
    val.x = (uint32_t)lt[ub + 0][d] | ((uint32_t)lt[ub + 1][d] << 16);
    val.y = (uint32_t)lt[ub + 2][d] | ((uint32_t)lt[ub + 3][d] << 16);
    val.z = (uint32_t)lt[ub + 4][d] | ((uint32_t)lt[ub + 5][d] << 16);
    val.w = (uint32_t)lt[ub + 6][d] | ((uint32_t)lt[ub + 7][d] << 16);
    *reinterpret_cast<uint4*>(hWbP + ((size_t)f * 128 + ks2) * 512 + l * 8) = val;
  }
}

// ======== launch 1: scan (512) and hw1 (256) INTERLEAVED (b%3==2 -> hw1).
__global__ __launch_bounds__(256) void k_scanhw1(const float* __restrict__ A,
                                                 const float* __restrict__ feat,
                                                 const float* __restrict__ W1,
                                                 const float* __restrict__ W2,
                                                 us* __restrict__ bitsT,
                                                 unsigned char* __restrict__ colpart,
                                                 float* __restrict__ oif,
                                                 us* __restrict__ oib,
                                                 us* __restrict__ hWb1,
                                                 us* __restrict__ hWbP1,
                                                 us* __restrict__ W2TbP) {
  __shared__ __align__(16) char smem[34176];
  const int b = blockIdx.x, t = threadIdx.x;
  const int r3 = b % 3;
  if (r3 == 2) {
    hw_selfstage(feat, W1, (b / 3) * 16, hWb1, hWbP1, smem);
    return;
  }
  const int sb = (b / 3) * 2 + r3;            // 0..511
  us* lds16 = reinterpret_cast<us*>(smem);    // [256 wv][8 u_loc]
  const int u0 = sb * 8;
  uint32_t cs[16];
#pragma unroll
  for (int k = 0; k < 16; ++k) cs[k] = 0;
#pragma unroll
  for (int rb = 0; rb < 2; ++rb) {
    f32x4 a[4][4];
#pragma unroll
    for (int r = 0; r < 4; ++r) {
      const f32x4* p = reinterpret_cast<const f32x4*>(A + (size_t)(u0 + rb * 4 + r) * NN + t * 16);
#pragma unroll
      for (int c = 0; c < 4; ++c) a[r][c] = p[c];
    }
#pragma unroll
    for (int r = 0; r < 4; ++r) {
      uint32_t m = 0;
#pragma unroll
      for (int c = 0; c < 4; ++c)
#pragma unroll
        for (int j = 0; j < 4; ++j) m |= (a[r][c][j] >= TH ? 1u : 0u) << (c * 4 + j);
      lds16[t * 8 + rb * 4 + r] = (us)m;
#pragma unroll
      for (int k = 0; k < 16; ++k) cs[k] += (m >> k) & 1u;
    }
  }
  uint4 pk;
  pk.x = cs[0]  | (cs[1]  << 8) | (cs[2]  << 16) | (cs[3]  << 24);
  pk.y = cs[4]  | (cs[5]  << 8) | (cs[6]  << 16) | (cs[7]  << 24);
  pk.z = cs[8]  | (cs[9]  << 8) | (cs[10] << 16) | (cs[11] << 24);
  pk.w = cs[12] | (cs[13] << 8) | (cs[14] << 16) | (cs[15] << 24);
  *reinterpret_cast<uint4*>(colpart + (size_t)sb * 4096 + t * 16) = pk;
  __syncthreads();
  uint4 wv4 = *reinterpret_cast<const uint4*>(&lds16[t * 8]);
  *reinterpret_cast<uint4*>(bitsT + (size_t)t * 4096 + u0) = wv4;
  if (t < 64) {
    const int r = t >> 3, part = t & 7;
    uint32_t s = 0;
#pragma unroll
    for (int wv = part * 32; wv < part * 32 + 32; ++wv)
      s += (uint32_t)__popc((uint32_t)lds16[wv * 8 + r]);
    s += __shfl_down(s, 4, 8);
    s += __shfl_down(s, 2, 8);
    s += __shfl_down(s, 1, 8);
    if (part == 0) {
      float val = rsqrtf((float)(s + 1u));
      oif[u0 + r] = val;
      oib[u0 + r] = f2bf(val);
    }
  }
  // W2 -> 16x16 B-frag panels (scan blocks sb 0..15)
  if (sb < 16) {
    const int base = sb * 4096 + t * 16;
#pragma unroll
    for (int e = 0; e < 16; ++e) {
      const int idx = base + e;
      const int frag = idx >> 9, pos = idx & 511;
      const int lc = pos >> 3, j = pos & 7;
      const int dt = frag >> 3, ks = frag & 7;
      const int k = ks * 32 + (lc >> 4) * 8 + j;
      const int d = dt * 16 + (lc & 15);
      W2TbP[idx] = f2bf(W2[k * 256 + d]);
    }
  }
}

// ======== launch 2 (fused): per block = 16 v (one bit-word column) x full 256 d.
// stage A: agg[16v][256d] = sum_u bit[u,v]*oib[u]*P1[u][d]  (K=4096, 16x16x32)
// stage B: ii reduce; h1 = relu((agg + oif*self)*ii + b1) -> out; g = bf16(h1*oif)
// stage C: P2 = g @ W2 (K=256) -> hWb2 rows + hWbP2 32x32 B-frag panels for spmm2.
__global__ __launch_bounds__(512, 2) void k_l1f(const us* __restrict__ bitsT,
                                                const us* __restrict__ hWbP1,
                                                const us* __restrict__ hWb1,
                                                const float* __restrict__ oif,
                                                const us* __restrict__ oib,
                                                const unsigned char* __restrict__ colpart,
                                                const us* __restrict__ W2TbP,
                                                float* __restrict__ ii_g,
                                                const float* __restrict__ b1,
                                                float* __restrict__ out,
                                                us* __restrict__ hWb2,
                                                us* __restrict__ hWbP2) {
  __shared__ __align__(16) uint32_t sc[128 * 4 * 2];   // 4 KB (ii partials)
  __shared__ us g[16][264];                            // oi*h1 bf16
  __shared__ us p2l[16][264];                          // P2 tile bf16
  __shared__ float ii_s[16];
  const int t = threadIdx.x, wv = blockIdx.x;
  const int lane = t & 63, w = t >> 6;
  const int V0 = wv * 16;
  const int l15 = lane & 15, l4 = lane >> 4;
  const uint32_t sh = (uint32_t)l15;

  const us* Ab = bitsT + (size_t)wv * 4096 + l4 * 8;
  const us* Ob = oib + l4 * 8;
  const us* Bp0 = hWbP1 + ((size_t)(w * 2 + 0) * 128) * 512 + lane * 8;
  const us* Bp1 = hWbP1 + ((size_t)(w * 2 + 1) * 128) * 512 + lane * 8;

  f32x4 acc0 = {0.f, 0.f, 0.f, 0.f}, acc1 = {0.f, 0.f, 0.f, 0.f};
  uint4 h[4]; s16x8 o[4], p0[4], p1[4];
#pragma unroll
  for (int sl = 0; sl < 4; ++sl) {
    h[sl]  = *reinterpret_cast<const uint4*>(Ab + sl * 32);
    o[sl]  = *reinterpret_cast<const s16x8*>(Ob + sl * 32);
    p0[sl] = *reinterpret_cast<const s16x8*>(Bp0 + (size_t)sl * 512);
    p1[sl] = *reinterpret_cast<const s16x8*>(Bp1 + (size_t)sl * 512);
  }
#pragma unroll 1
  for (int it = 0; it < 32; ++it) {
#pragma unroll
    for (int sl = 0; sl < 4; ++sl) {
      union { s16x8 v; uint32_t u[4]; } af;
      const uint32_t* ou = reinterpret_cast<const uint32_t*>(&o[sl]);
      uint32_t m;
      m = (h[sl].x >> sh) & 0x10001u; af.u[0] = ou[0] & ((m << 16) - m);
      m = (h[sl].y >> sh) & 0x10001u; af.u[1] = ou[1] & ((m << 16) - m);
      m = (h[sl].z >> sh) & 0x10001u; af.u[2] = ou[2] & ((m << 16) - m);
      m = (h[sl].w >> sh) & 0x10001u; af.u[3] = ou[3] & ((m << 16) - m);
      acc0 = __builtin_amdgcn_mfma_f32_16x16x32_bf16(af.v, p0[sl], acc0, 0, 0, 0);
      acc1 = __builtin_amdgcn_mfma_f32_16x16x32_bf16(af.v, p1[sl], acc1, 0, 0, 0);
      const int ns = (it * 4 + sl + 4) & 127;      // wraps at tail (unused)
      h[sl]  = *reinterpret_cast<const uint4*>(Ab + ns * 32);
      o[sl]  = *reinterpret_cast<const s16x8*>(Ob + ns * 32);
      p0[sl] = *reinterpret_cast<const s16x8*>(Bp0 + (size_t)ns * 512);
      p1[sl] = *reinterpret_cast<const s16x8*>(Bp1 + (size_t)ns * 512);
    }
  }

  // ---- ii reduce for this block's 16 v (drain window)
  {
    const int v4 = t & 3, c = t >> 2;            // 128 chunks x 4 rows
    uint32_t s0 = 0, s1 = 0;
#pragma unroll
    for (int r = 0; r < 4; ++r) {
      uint32_t x = *reinterpret_cast<const uint32_t*>(colpart + (size_t)(c * 4 + r) * 4096 + V0 + v4 * 4);
      s0 += x & 0x00FF00FFu;
      s1 += (x >> 8) & 0x00FF00FFu;
    }
    sc[(c * 4 + v4) * 2] = s0;
    sc[(c * 4 + v4) * 2 + 1] = s1;
  }
  __syncthreads();
  if (t < 16) {
    const int v4b = t >> 2, sub = t & 3;
    const int reg = sub & 1, hi = sub >> 1;
    uint32_t s = 0;
#pragma unroll 8
    for (int c2 = 0; c2 < 128; ++c2)
      s += (sc[(c2 * 4 + v4b) * 2 + reg] >> (hi * 16)) & 0xFFFFu;
    float val = rsqrtf((float)(s + 1u));
    ii_s[t] = val;
    ii_g[V0 + t] = val;
  }
  __syncthreads();

  // ---- epilogue: h1 + g   (C/D 16x16: row=l4*4+r, col=l15)
  {
    const int d0 = w * 32 + l15, d1 = d0 + 16;
    const float bv0 = b1[d0], bv1 = b1[d1];
#pragma unroll
    for (int r = 0; r < 4; ++r) {
      const int vloc = l4 * 4 + r;
      const int v = V0 + vloc;
      const float iv = ii_s[vloc];
      const float ov = oif[v];
      const float self0 = bf2f(hWb1[(size_t)v * DD + d0]);
      const float self1 = bf2f(hWb1[(size_t)v * DD + d1]);
      const float h10 = fmaxf((acc0[r] + ov * self0) * iv + bv0, 0.f);
      const float h11 = fmaxf((acc1[r] + ov * self1) * iv + bv1, 0.f);
      out[(size_t)v * DD + d0] = h10;
      out[(size_t)v * DD + d1] = h11;
      g[vloc][d0] = f2bf(h10 * ov);
      g[vloc][d1] = f2bf(h11 * ov);
    }
  }
  __syncthreads();

  // ---- stage C: P2 = g @ W2 (K=256); wave w owns d2 slice w*32 (2 dt16)
  f32x4 q0 = {0.f, 0.f, 0.f, 0.f}, q1 = {0.f, 0.f, 0.f, 0.f};
#pragma unroll
  for (int ks = 0; ks < 8; ++ks) {
    s16x8 af = *reinterpret_cast<const s16x8*>(&g[l15][ks * 32 + l4 * 8]);
    s16x8 w0 = *reinterpret_cast<const s16x8*>(W2TbP + ((size_t)(w * 2 + 0) * 8 + ks) * 512 + lane * 8);
    s16x8 w1 = *reinterpret_cast<const s16x8*>(W2TbP + ((size_t)(w * 2 + 1) * 8 + ks) * 512 + lane * 8);
    q0 = __builtin_amdgcn_mfma_f32_16x16x32_bf16(af, w0, q0, 0, 0, 0);
    q1 = __builtin_amdgcn_mfma_f32_16x16x32_bf16(af, w1, q1, 0, 0, 0);
  }
#pragma unroll
  for (int r = 0; r < 4; ++r) {
    const int vloc = l4 * 4 + r;
    p2l[vloc][w * 32 + l15] = f2bf(q0[r]);
    p2l[vloc][w * 32 + 16 + l15] = f2bf(q1[r]);
  }
  __syncthreads();

  // ---- writes: hWb2 rows + hWbP2 32x32 B-frag panels (sg = wv)
  {
    const int row = t >> 5, d8 = (t & 31) * 8;
    uint4 val;
    val.x = (uint32_t)p2l[row][d8 + 0] | ((uint32_t)p2l[row][d8 + 1] << 16);
    val.y = (uint32_t)p2l[row][d8 + 2] | ((uint32_t)p2l[row][d8 + 3] << 16);
    val.z = (uint32_t)p2l[row][d8 + 4] | ((uint32_t)p2l[row][d8 + 5] << 16);
    val.w = (uint32_t)p2l[row][d8 + 6] | ((uint32_t)p2l[row][d8 + 7] << 16);
    *reinterpret_cast<uint4*>(hWb2 + (size_t)(V0 + row) * DD + d8) = val;
  }
  {
    const int f = t >> 6, lc = t & 63;
    const int ub = (lc >> 5) * 8;
    const int d = f * 32 + (lc & 31);
    uint4 val;
    val.x = (uint32_t)p2l[ub + 0][d] | ((uint32_t)p2l[ub + 1][d] << 16);
    val.y = (uint32_t)p2l[ub + 2][d] | ((uint32_t)p2l[ub + 3][d] << 16);
    val.z = (uint32_t)p2l[ub + 4][d] | ((uint32_t)p2l[ub + 5][d] << 16);
    val.w = (uint32_t)p2l[ub + 6][d] | ((uint32_t)p2l[ub + 7][d] << 16);
    *reinterpret_cast<uint4*>(hWbP2 + ((size_t)f * 256 + wv) * 512 + lc * 8) = val;
  }
}

// ======== launch 3: layer-2 SpMM (r10-proven lean variant, pre-scaled panels).
// out[v][d] = relu((sum_u bit*P2[u][d] + P2[v][d]) * ii[v] + b[d])
// Grid 256 = 64vt x 4dq XCD-swizzled; block 512 = 8 waves = 4kc x 2mi.
__global__ __launch_bounds__(512, 2) void k_spmm2(const us* __restrict__ bitsT,
                                                  const us* __restrict__ hWbP,
                                                  const us* __restrict__ hWb,
                                                  const float* __restrict__ ii_g,
                                                  const float* __restrict__ bias,
                                                  float* __restrict__ dst) {
  __shared__ float lds[4 * 64 * 68];
  __shared__ float ii_s[64];
  const int t = threadIdx.x, bq = blockIdx.x;
  const int lane = t & 63, w = t >> 6;
  const int mi = w & 1, kc = w >> 1;
  const int xcd = bq & 7, jj = bq >> 3;
  const int vt = xcd * 8 + (jj >> 2), dq = jj & 3;
  const int V0 = vt * 64, D0 = dq * 64;

  const int l31 = lane & 31, l5 = lane >> 5;
  const uint32_t sh = lane & 15;
  const int wvl = vt * 4 + mi * 2 + ((lane >> 4) & 1);
  const us* Ab = bitsT + (size_t)wvl * 4096 + kc * 1024 + l5 * 8;
  const us* Bp0 = hWbP + ((size_t)(dq * 2 + 0) * 256 + kc * 64) * 512 + lane * 8;
  const us* Bp1 = hWbP + ((size_t)(dq * 2 + 1) * 256 + kc * 64) * 512 + lane * 8;

  f32x16 acc0, acc1;
#pragma unroll
  for (int q = 0; q < 16; ++q) { acc0[q] = 0.f; acc1[q] = 0.f; }

  uint4 h[4]; s16x8 p0[4], p1[4];
#pragma unroll
  for (int sl = 0; sl < 4; ++sl) {
    h[sl]  = *reinterpret_cast<const uint4*>(Ab + sl * 16);
    p0[sl] = *reinterpret_cast<const s16x8*>(Bp0 + (size_t)sl * 512);
    p1[sl] = *reinterpret_cast<const s16x8*>(Bp1 + (size_t)sl * 512);
  }

#pragma unroll 1
  for (int it = 0; it < 16; ++it) {
#pragma unroll
    for (int sl = 0; sl < 4; ++sl) {
      union { s16x8 v; uint32_t u[4]; } af;
      uint32_t m;
      m = (h[sl].x >> sh) & 0x10001u; af.u[0] = m * 0x3F80u;
      m = (h[sl].y >> sh) & 0x10001u; af.u[1] = m * 0x3F80u;
      m = (h[sl].z >> sh) & 0x10001u; af.u[2] = m * 0x3F80u;
      m = (h[sl].w >> sh) & 0x10001u; af.u[3] = m * 0x3F80u;
      acc0 = __builtin_amdgcn_mfma_f32_32x32x16_bf16(af.v, p0[sl], acc0, 0, 0, 0);
      acc1 = __builtin_amdgcn_mfma_f32_32x32x16_bf16(af.v, p1[sl], acc1, 0, 0, 0);
      const int ns = (it * 4 + sl + 4) & 63;       // wraps at tail (unused)
      h[sl]  = *reinterpret_cast<const uint4*>(Ab + ns * 16);
      p0[sl] = *reinterpret_cast<const s16x8*>(Bp0 + (size_t)ns * 512);
      p1[sl] = *reinterpret_cast<const s16x8*>(Bp1 + (size_t)ns * 512);
    }
  }

  if (t < 64) ii_s[t] = ii_g[V0 + t];

  // dump: C/D 32x32: col=lane&31, row=(reg&3)+8*(reg>>2)+4*(lane>>5)
  float* buf = lds + (size_t)kc * (64 * 68);
#pragma unroll
  for (int reg = 0; reg < 16; ++reg) {
    const int row = (reg & 3) + 8 * (reg >> 2) + 4 * l5;
    buf[(mi * 32 + row) * 68 + l31] = acc0[reg];
    buf[(mi * 32 + row) * 68 + 32 + l31] = acc1[reg];
  }
  __syncthreads();

  const int vloc = t >> 3, d8 = (t & 7) * 8;
  const int v = V0 + vloc;
  const float* base = lds + vloc * 68 + d8;
  f32x4 s0v = *reinterpret_cast<const f32x4*>(base);
  f32x4 s1v = *reinterpret_cast<const f32x4*>(base + 4);
#pragma unroll
  for (int q = 1; q < 4; ++q) {
    s0v += *reinterpret_cast<const f32x4*>(base + q * (64 * 68));
    s1v += *reinterpret_cast<const f32x4*>(base + q * (64 * 68) + 4);
  }
  union { s16x8 v; us u[8]; } self;
  self.v = *reinterpret_cast<const s16x8*>(hWb + (size_t)v * DD + D0 + d8);
  const float iv = ii_s[vloc];
  const f32x4 bi0 = *reinterpret_cast<const f32x4*>(bias + D0 + d8);
  const f32x4 bi1 = *reinterpret_cast<const f32x4*>(bias + D0 + d8 + 4);
  f32x4 o0, o1;
#pragma unroll
  for (int e = 0; e < 4; ++e) {
    o0[e] = fmaxf((s0v[e] + bf2f(self.u[e])) * iv + bi0[e], 0.f);
    o1[e] = fmaxf((s1v[e] + bf2f(self.u[e + 4])) * iv + bi1[e], 0.f);
  }
  f32x4* po = reinterpret_cast<f32x4*>(dst + (size_t)v * DD + D0 + d8);
  po[0] = o0; po[1] = o1;
}

extern "C" void kernel_launch(void* const* d_in, const int* in_sizes, int n_in,
                              void* d_out, int out_size, void* d_ws, size_t ws_size,
                              hipStream_t stream) {
  const float* A    = (const float*)d_in[0];
  const float* feat = (const float*)d_in[1];
  const float* W1   = (const float*)d_in[2];
  const float* b1   = (const float*)d_in[3];
  const float* W2   = (const float*)d_in[4];
  const float* b2   = (const float*)d_in[5];
  float* out = (float*)d_out;
  char* ws = (char*)d_ws;

  us*            bitsT   = (us*)ws;                                   // 2 MiB
  unsigned char* colpart = (unsigned char*)(ws + (2u << 20));         // 2 MiB
  us*            hWbP1   = (us*)(ws + (4u << 20));                    // 2 MiB
  us*            hWb1    = (us*)(ws + (6u << 20));                    // 2 MiB
  us*            hWbP2   = (us*)(ws + (8u << 20));                    // 2 MiB
  us*            hWb2    = (us*)(ws + (10u << 20));                   // 2 MiB
  us*            W2TbP   = (us*)(ws + (12u << 20));                   // 128 KiB
  float*         oif     = (float*)(ws + (12u << 20) + (1u << 17));   // 16 KiB
  us*            oib     = (us*)(ws + (12u << 20) + (1u << 17) + (16u << 10));
  float*         ii_g    = (float*)(ws + (12u << 20) + (1u << 17) + (24u << 10));

  // 1: A-scan + feat@W1 interleaved (+ W2 panels)
  k_scanhw1<<<768, 256, 0, stream>>>(A, feat, W1, W2, bitsT, colpart, oif, oib,
                                     hWb1, hWbP1, W2TbP);
  // 2: fused layer-1 spmm + (oi*h1)@W2 panel build
  k_l1f<<<256, 512, 0, stream>>>(bitsT, hWbP1, hWb1, oif, oib, colpart, W2TbP,
                                 ii_g, b1, out, hWb2, hWbP2);
  // 3: layer-2 spmm
  k_spmm2<<<256, 512, 0, stream>>>(bitsT, hWbP2, hWb2, ii_g, b2,
                                   out + (size_t)NN * DD);
}

// Round 12
// 70.327 us; speedup vs baseline: 1.1466x; 1.1466x over previous
//
#include <hip/hip_runtime.h>
#include <stdint.h>

#define NN 4096
#define DD 256
#define TH 0.04f

typedef __attribute__((ext_vector_type(4))) float f32x4;
typedef __attribute__((ext_vector_type(16))) float f32x16;
typedef __attribute__((ext_vector_type(8))) short s16x8;
typedef unsigned short us;

__device__ __forceinline__ us f2bf(float f) {
  union { float f; uint32_t u; } x; x.f = f;
  uint32_t u = x.u;
  return (us)((u + 0x7FFFu + ((u >> 16) & 1u)) >> 16);  // RNE
}
__device__ __forceinline__ float bf2f(us h) {
  union { uint32_t u; float f; } x; x.u = ((uint32_t)h) << 16;
  return x.f;
}

// ======== hw (self-staged W): P1 = feat@W1 -> hWb [u][d] bf16 + 32x32 B-frag
// panels hWbP[dt(8)][sg(256)][512]. 16 u-rows/block, 256 threads.
__device__ __forceinline__ void hw_selfstage(const float* __restrict__ H,
                                             const float* __restrict__ W,
                                             int u0,
                                             us* __restrict__ hWb,
                                             us* __restrict__ hWbP,
                                             char* smem) {
  us (*hs)[264] = reinterpret_cast<us(*)[264]>(smem);
  us (*wt)[34]  = reinterpret_cast<us(*)[34]>(smem + 16 * 264 * 2);
  us (*lt)[260] = reinterpret_cast<us(*)[260]>(smem + 16 * 264 * 2 + 256 * 34 * 2);
  const int t = threadIdx.x;
#pragma unroll
  for (int rep = 0; rep < 4; ++rep) {
    const int flat = rep * 256 + t;
    const int row = flat >> 6, c4 = (flat & 63) * 4;
    f32x4 v = *reinterpret_cast<const f32x4*>(H + (size_t)(u0 + row) * DD + c4);
    uint2 pw;
    pw.x = (uint32_t)f2bf(v[0]) | ((uint32_t)f2bf(v[1]) << 16);
    pw.y = (uint32_t)f2bf(v[2]) | ((uint32_t)f2bf(v[3]) << 16);
    *reinterpret_cast<uint2*>(&hs[row][c4]) = pw;
  }
  const int lane = t & 63, w = t >> 6, l15 = lane & 15, l4 = lane >> 4;
  const f32x4 z = {0.f, 0.f, 0.f, 0.f};
  f32x4 acc[4];
#pragma unroll
  for (int jn = 0; jn < 4; ++jn) acc[jn] = z;
#pragma unroll 1
  for (int ks = 0; ks < 8; ++ks) {
    __syncthreads();
#pragma unroll
    for (int rr = 0; rr < 8; ++rr) {
      const int flat = rr * 256 + t;
      const int k = flat >> 6, d0 = (flat & 63) * 4;
      f32x4 wv = *reinterpret_cast<const f32x4*>(W + (size_t)(ks * 32 + k) * DD + d0);
      wt[d0 + 0][k] = f2bf(wv[0]);
      wt[d0 + 1][k] = f2bf(wv[1]);
      wt[d0 + 2][k] = f2bf(wv[2]);
      wt[d0 + 3][k] = f2bf(wv[3]);
    }
    __syncthreads();
    s16x8 af = *reinterpret_cast<const s16x8*>(&hs[l15][ks * 32 + l4 * 8]);
#pragma unroll
    for (int jn = 0; jn < 4; ++jn) {
      const int dt = w * 4 + jn;
      s16x8 bf = *reinterpret_cast<const s16x8*>(&wt[dt * 16 + l15][l4 * 8]);
      acc[jn] = __builtin_amdgcn_mfma_f32_16x16x32_bf16(af, bf, acc[jn], 0, 0, 0);
    }
  }
#pragma unroll
  for (int jn = 0; jn < 4; ++jn) {
    const int d = w * 64 + jn * 16 + l15;
#pragma unroll
    for (int r = 0; r < 4; ++r) {
      const int ul = l4 * 4 + r;              // C/D 16x16: row=l4*4+r, col=l15
      us hv = f2bf(acc[jn][r]);
      hWb[(size_t)(u0 + ul) * DD + d] = hv;
      lt[ul][d] = hv;
    }
  }
  __syncthreads();
  const int sg = u0 >> 4;
#pragma unroll
  for (int cc = 0; cc < 2; ++cc) {
    const int c = t * 2 + cc;
    const int dt = c >> 6, lc = c & 63;
    const int ub = (lc >> 5) * 8;
    const int d = dt * 32 + (lc & 31);
    uint4 val;
    val.x = (uint32_t)lt[ub + 0][d] | ((uint32_t)lt[ub + 1][d] << 16);
    val.y = (uint32_t)lt[ub + 2][d] | ((uint32_t)lt[ub + 3][d] << 16);
    val.z = (uint32_t)lt[ub + 4][d] | ((uint32_t)lt[ub + 5][d] << 16);
    val.w = (uint32_t)lt[ub + 6][d] | ((uint32_t)lt[ub + 7][d] << 16);
    *reinterpret_cast<uint4*>(hWbP + ((size_t)dt * 256 + sg) * 512 + lc * 8) = val;
  }
}

// ======== launch 1: scan (512) and hw1 (256) INTERLEAVED (b%3==2 -> hw1).
__global__ __launch_bounds__(256) void k_scanhw1(const float* __restrict__ A,
                                                 const float* __restrict__ feat,
                                                 const float* __restrict__ W1,
                                                 const float* __restrict__ W2,
                                                 us* __restrict__ bitsT,
                                                 unsigned char* __restrict__ colpart,
                                                 float* __restrict__ oif,
                                                 us* __restrict__ oib,
                                                 us* __restrict__ hWb1,
                                                 us* __restrict__ hWbP1,
                                                 us* __restrict__ W2TbP) {
  __shared__ __align__(16) char smem[34176];
  const int b = blockIdx.x, t = threadIdx.x;
  const int r3 = b % 3;
  if (r3 == 2) {
    hw_selfstage(feat, W1, (b / 3) * 16, hWb1, hWbP1, smem);
    return;
  }
  const int sb = (b / 3) * 2 + r3;            // 0..511
  us* lds16 = reinterpret_cast<us*>(smem);    // [256 wv][8 u_loc]
  const int u0 = sb * 8;
  uint32_t cs[16];
#pragma unroll
  for (int k = 0; k < 16; ++k) cs[k] = 0;
#pragma unroll
  for (int rb = 0; rb < 2; ++rb) {
    f32x4 a[4][4];
#pragma unroll
    for (int r = 0; r < 4; ++r) {
      const f32x4* p = reinterpret_cast<const f32x4*>(A + (size_t)(u0 + rb * 4 + r) * NN + t * 16);
#pragma unroll
      for (int c = 0; c < 4; ++c) a[r][c] = p[c];
    }
#pragma unroll
    for (int r = 0; r < 4; ++r) {
      uint32_t m = 0;
#pragma unroll
      for (int c = 0; c < 4; ++c)
#pragma unroll
        for (int j = 0; j < 4; ++j) m |= (a[r][c][j] >= TH ? 1u : 0u) << (c * 4 + j);
      lds16[t * 8 + rb * 4 + r] = (us)m;
#pragma unroll
      for (int k = 0; k < 16; ++k) cs[k] += (m >> k) & 1u;
    }
  }
  uint4 pk;
  pk.x = cs[0]  | (cs[1]  << 8) | (cs[2]  << 16) | (cs[3]  << 24);
  pk.y = cs[4]  | (cs[5]  << 8) | (cs[6]  << 16) | (cs[7]  << 24);
  pk.z = cs[8]  | (cs[9]  << 8) | (cs[10] << 16) | (cs[11] << 24);
  pk.w = cs[12] | (cs[13] << 8) | (cs[14] << 16) | (cs[15] << 24);
  *reinterpret_cast<uint4*>(colpart + (size_t)sb * 4096 + t * 16) = pk;
  __syncthreads();
  uint4 wv4 = *reinterpret_cast<const uint4*>(&lds16[t * 8]);
  *reinterpret_cast<uint4*>(bitsT + (size_t)t * 4096 + u0) = wv4;
  if (t < 64) {
    const int r = t >> 3, part = t & 7;
    uint32_t s = 0;
#pragma unroll
    for (int wv = part * 32; wv < part * 32 + 32; ++wv)
      s += (uint32_t)__popc((uint32_t)lds16[wv * 8 + r]);
    s += __shfl_down(s, 4, 8);
    s += __shfl_down(s, 2, 8);
    s += __shfl_down(s, 1, 8);
    if (part == 0) {
      float val = rsqrtf((float)(s + 1u));
      oif[u0 + r] = val;
      oib[u0 + r] = f2bf(val);
    }
  }
  // W2 -> 16x16 B-frag panels (scan blocks sb 0..15)
  if (sb < 16) {
    const int base = sb * 4096 + t * 16;
#pragma unroll
    for (int e = 0; e < 16; ++e) {
      const int idx = base + e;
      const int frag = idx >> 9, pos = idx & 511;
      const int lc = pos >> 3, j = pos & 7;
      const int dt = frag >> 3, ks = frag & 7;
      const int k = ks * 32 + (lc >> 4) * 8 + j;
      const int d = dt * 16 + (lc & 15);
      W2TbP[idx] = f2bf(W2[k * 256 + d]);
    }
  }
}

// ======== hw2: h1@W2 via pre-built W2 panels; stages h1 from bf16 copy h1b
// (no conversion); epilogue folds oif[u]. 256 blocks x 256 thr, 16 rows.
__global__ __launch_bounds__(256) void k_hw2(const us* __restrict__ h1b,
                                             const us* __restrict__ WP,
                                             const float* __restrict__ oif,
                                             us* __restrict__ hWb,
                                             us* __restrict__ hWbP) {
  __shared__ us hs[16][264];
  __shared__ us lt[16][260];
  const int t = threadIdx.x;
  const int u0 = blockIdx.x * 16;
#pragma unroll
  for (int rep = 0; rep < 2; ++rep) {
    const int flat = rep * 256 + t;             // 512 units of 8 us
    const int row = flat >> 5, c8 = (flat & 31) * 8;
    *reinterpret_cast<uint4*>(&hs[row][c8]) =
        *reinterpret_cast<const uint4*>(h1b + (size_t)(u0 + row) * DD + c8);
  }
  __syncthreads();
  const int lane = t & 63, w = t >> 6, l15 = lane & 15, l4 = lane >> 4;
  const f32x4 z = {0.f, 0.f, 0.f, 0.f};
  f32x4 acc[4];
#pragma unroll
  for (int jn = 0; jn < 4; ++jn) acc[jn] = z;
#pragma unroll
  for (int ks = 0; ks < 8; ++ks) {
    s16x8 af = *reinterpret_cast<const s16x8*>(&hs[l15][ks * 32 + l4 * 8]);
#pragma unroll
    for (int jn = 0; jn < 4; ++jn) {
      const int dt = w * 4 + jn;
      s16x8 bf = *reinterpret_cast<const s16x8*>(WP + ((size_t)dt * 8 + ks) * 512 + lane * 8);
      acc[jn] = __builtin_amdgcn_mfma_f32_16x16x32_bf16(af, bf, acc[jn], 0, 0, 0);
    }
  }
  float oifv[4];
#pragma unroll
  for (int r = 0; r < 4; ++r) oifv[r] = oif[u0 + l4 * 4 + r];
#pragma unroll
  for (int jn = 0; jn < 4; ++jn) {
    const int d = w * 64 + jn * 16 + l15;
#pragma unroll
    for (int r = 0; r < 4; ++r) {
      const int ul = l4 * 4 + r;
      us hv = f2bf(acc[jn][r] * oifv[r]);
      hWb[(size_t)(u0 + ul) * DD + d] = hv;
      lt[ul][d] = hv;
    }
  }
  __syncthreads();
  const int sg = u0 >> 4;
#pragma unroll
  for (int cc = 0; cc < 2; ++cc) {
    const int c = t * 2 + cc;
    const int dt = c >> 6, lc = c & 63;
    const int ub = (lc >> 5) * 8;
    const int d = dt * 32 + (lc & 31);
    uint4 val;
    val.x = (uint32_t)lt[ub + 0][d] | ((uint32_t)lt[ub + 1][d] << 16);
    val.y = (uint32_t)lt[ub + 2][d] | ((uint32_t)lt[ub + 3][d] << 16);
    val.z = (uint32_t)lt[ub + 4][d] | ((uint32_t)lt[ub + 5][d] << 16);
    val.w = (uint32_t)lt[ub + 6][d] | ((uint32_t)lt[ub + 7][d] << 16);
    *reinterpret_cast<uint4*>(hWbP + ((size_t)dt * 256 + sg) * 512 + lc * 8) = val;
  }
}

// ======== fused SpMM (template L1):
// L1=1: out = relu((sum_u bit*oib[u]*P[u][d] + oif[v]*P[v][d])*ii + b); computes ii;
//       also emits h1b = bf16(out) for hw2's stage.
// L1=0: panels pre-scaled by oi -> out = relu((sum_u bit*P[u][d] + P[v][d])*ii + b).
// Grid 256 = 64vt x 4dq XCD-swizzled; block 512 = 8 waves = 4kc x 2mi.
template <int L1>
__global__ __launch_bounds__(512, 2) void k_spmm(const us* __restrict__ bitsT,
                                                 const us* __restrict__ hWbP,
                                                 const us* __restrict__ hWb,
                                                 const float* __restrict__ oif,
                                                 const us* __restrict__ oib,
                                                 const unsigned char* __restrict__ colpart,
                                                 float* __restrict__ ii_g,
                                                 const float* __restrict__ bias,
                                                 float* __restrict__ dst,
                                                 us* __restrict__ h1b) {
  __shared__ float lds[4 * 64 * 68];
  __shared__ float ii_s[64];
  const int t = threadIdx.x, bq = blockIdx.x;
  const int lane = t & 63, w = t >> 6;
  const int mi = w & 1, kc = w >> 1;
  const int xcd = bq & 7, jj = bq >> 3;
  const int vt = xcd * 8 + (jj >> 2), dq = jj & 3;
  const int V0 = vt * 64, D0 = dq * 64;

  const int l31 = lane & 31, l5 = lane >> 5;
  const uint32_t sh = lane & 15;
  const int wvl = vt * 4 + mi * 2 + ((lane >> 4) & 1);
  const us* Ab = bitsT + (size_t)wvl * 4096 + kc * 1024 + l5 * 8;
  const us* Ob = oib + kc * 1024 + l5 * 8;
  const us* Bp0 = hWbP + ((size_t)(dq * 2 + 0) * 256 + kc * 64) * 512 + lane * 8;
  const us* Bp1 = hWbP + ((size_t)(dq * 2 + 1) * 256 + kc * 64) * 512 + lane * 8;

  f32x16 acc0, acc1;
#pragma unroll
  for (int q = 0; q < 16; ++q) { acc0[q] = 0.f; acc1[q] = 0.f; }

  uint4 h[4]; s16x8 o[4], p0[4], p1[4];
#pragma unroll
  for (int sl = 0; sl < 4; ++sl) {
    h[sl]  = *reinterpret_cast<const uint4*>(Ab + sl * 16);
    if (L1) o[sl] = *reinterpret_cast<const s16x8*>(Ob + sl * 16);
    p0[sl] = *reinterpret_cast<const s16x8*>(Bp0 + (size_t)sl * 512);
    p1[sl] = *reinterpret_cast<const s16x8*>(Bp1 + (size_t)sl * 512);
  }

#pragma unroll 1
  for (int it = 0; it < 16; ++it) {
#pragma unroll
    for (int sl = 0; sl < 4; ++sl) {
      union { s16x8 v; uint32_t u[4]; } af;
      uint32_t m;
      if (L1) {
        const uint32_t* ou = reinterpret_cast<const uint32_t*>(&o[sl]);
        m = (h[sl].x >> sh) & 0x10001u; af.u[0] = ou[0] & ((m << 16) - m);
        m = (h[sl].y >> sh) & 0x10001u; af.u[1] = ou[1] & ((m << 16) - m);
        m = (h[sl].z >> sh) & 0x10001u; af.u[2] = ou[2] & ((m << 16) - m);
        m = (h[sl].w >> sh) & 0x10001u; af.u[3] = ou[3] & ((m << 16) - m);
      } else {
        m = (h[sl].x >> sh) & 0x10001u; af.u[0] = m * 0x3F80u;
        m = (h[sl].y >> sh) & 0x10001u; af.u[1] = m * 0x3F80u;
        m = (h[sl].z >> sh) & 0x10001u; af.u[2] = m * 0x3F80u;
        m = (h[sl].w >> sh) & 0x10001u; af.u[3] = m * 0x3F80u;
      }
      acc0 = __builtin_amdgcn_mfma_f32_32x32x16_bf16(af.v, p0[sl], acc0, 0, 0, 0);
      acc1 = __builtin_amdgcn_mfma_f32_32x32x16_bf16(af.v, p1[sl], acc1, 0, 0, 0);
      const int ns = (it * 4 + sl + 4) & 63;       // wraps at tail (unused)
      h[sl]  = *reinterpret_cast<const uint4*>(Ab + ns * 16);
      if (L1) o[sl] = *reinterpret_cast<const s16x8*>(Ob + ns * 16);
      p0[sl] = *reinterpret_cast<const s16x8*>(Bp0 + (size_t)ns * 512);
      p1[sl] = *reinterpret_cast<const s16x8*>(Bp1 + (size_t)ns * 512);
    }
  }

  // ii: compute (L1, in the MFMA drain window) or load cached
  if (L1) {
    uint32_t* sc = reinterpret_cast<uint32_t*>(lds);
    const int v4 = t & 15, c = t >> 4;
    uint32_t s0 = 0, s1 = 0;
#pragma unroll 4
    for (int r = 0; r < 16; ++r) {
      uint32_t x = *reinterpret_cast<const uint32_t*>(colpart + (size_t)(c * 16 + r) * 4096 + V0 + v4 * 4);
      s0 += x & 0x00FF00FFu;
      s1 += (x >> 8) & 0x00FF00FFu;
    }
    sc[(c * 16 + v4) * 2] = s0;
    sc[(c * 16 + v4) * 2 + 1] = s1;
    __syncthreads();
    if (t < 64) {
      const int v4b = t >> 2, sub = t & 3;
      const int reg = sub & 1, hi = sub >> 1;
      uint32_t s = 0;
#pragma unroll
      for (int cc = 0; cc < 32; ++cc)
        s += (sc[(cc * 16 + v4b) * 2 + reg] >> (hi * 16)) & 0xFFFFu;
      float val = rsqrtf((float)(s + 1u));
      ii_s[t] = val;
      ii_g[V0 + t] = val;
    }
    __syncthreads();        // sc reads done before dump overwrites lds
  } else {
    if (t < 64) ii_s[t] = ii_g[V0 + t];
  }

  // dump: C/D 32x32: col=lane&31, row=(reg&3)+8*(reg>>2)+4*(lane>>5)
  float* buf = lds + (size_t)kc * (64 * 68);
#pragma unroll
  for (int reg = 0; reg < 16; ++reg) {
    const int row = (reg & 3) + 8 * (reg >> 2) + 4 * l5;
    buf[(mi * 32 + row) * 68 + l31] = acc0[reg];
    buf[(mi * 32 + row) * 68 + 32 + l31] = acc1[reg];
  }
  __syncthreads();

  const int vloc = t >> 3, d8 = (t & 7) * 8;
  const int v = V0 + vloc;
  const float* base = lds + vloc * 68 + d8;
  f32x4 s0v = *reinterpret_cast<const f32x4*>(base);
  f32x4 s1v = *reinterpret_cast<const f32x4*>(base + 4);
#pragma unroll
  for (int q = 1; q < 4; ++q) {
    s0v += *reinterpret_cast<const f32x4*>(base + q * (64 * 68));
    s1v += *reinterpret_cast<const f32x4*>(base + q * (64 * 68) + 4);
  }
  union { s16x8 v; us u[8]; } self;
  self.v = *reinterpret_cast<const s16x8*>(hWb + (size_t)v * DD + D0 + d8);
  const float iv = ii_s[vloc];
  const float ov = L1 ? oif[v] : 1.0f;
  const f32x4 bi0 = *reinterpret_cast<const f32x4*>(bias + D0 + d8);
  const f32x4 bi1 = *reinterpret_cast<const f32x4*>(bias + D0 + d8 + 4);
  f32x4 o0, o1;
#pragma unroll
  for (int e = 0; e < 4; ++e) {
    o0[e] = fmaxf((s0v[e] + ov * bf2f(self.u[e])) * iv + bi0[e], 0.f);
    o1[e] = fmaxf((s1v[e] + ov * bf2f(self.u[e + 4])) * iv + bi1[e], 0.f);
  }
  f32x4* po = reinterpret_cast<f32x4*>(dst + (size_t)v * DD + D0 + d8);
  po[0] = o0; po[1] = o1;
  if (L1) {
    uint4 hb;
    hb.x = (uint32_t)f2bf(o0[0]) | ((uint32_t)f2bf(o0[1]) << 16);
    hb.y = (uint32_t)f2bf(o0[2]) | ((uint32_t)f2bf(o0[3]) << 16);
    hb.z = (uint32_t)f2bf(o1[0]) | ((uint32_t)f2bf(o1[1]) << 16);
    hb.w = (uint32_t)f2bf(o1[2]) | ((uint32_t)f2bf(o1[3]) << 16);
    *reinterpret_cast<uint4*>(h1b + (size_t)v * DD + D0 + d8) = hb;
  }
}

extern "C" void kernel_launch(void* const* d_in, const int* in_sizes, int n_in,
                              void* d_out, int out_size, void* d_ws, size_t ws_size,
                              hipStream_t stream) {
  const float* A    = (const float*)d_in[0];
  const float* feat = (const float*)d_in[1];
  const float* W1   = (const float*)d_in[2];
  const float* b1   = (const float*)d_in[3];
  const float* W2   = (const float*)d_in[4];
  const float* b2   = (const float*)d_in[5];
  float* out = (float*)d_out;
  char* ws = (char*)d_ws;

  us*            bitsT   = (us*)ws;                                   // 2 MiB
  unsigned char* colpart = (unsigned char*)(ws + (2u << 20));         // 2 MiB
  us*            hWbP1   = (us*)(ws + (4u << 20));                    // 2 MiB
  us*            hWb1    = (us*)(ws + (6u << 20));                    // 2 MiB
  us*            hWbP2   = (us*)(ws + (8u << 20));                    // 2 MiB
  us*            hWb2    = (us*)(ws + (10u << 20));                   // 2 MiB
  us*            h1b     = (us*)(ws + (12u << 20));                   // 2 MiB
  us*            W2TbP   = (us*)(ws + (14u << 20));                   // 128 KiB
  float*         oif     = (float*)(ws + (14u << 20) + (1u << 17));   // 16 KiB
  us*            oib     = (us*)(ws + (14u << 20) + (1u << 17) + (16u << 10));
  float*         ii_g    = (float*)(ws + (14u << 20) + (1u << 17) + (24u << 10));

  // 1: A-scan + feat@W1 interleaved (+ W2 panels)
  k_scanhw1<<<768, 256, 0, stream>>>(A, feat, W1, W2, bitsT, colpart, oif, oib,
                                     hWb1, hWbP1, W2TbP);
  // 2: layer-1 spmm (computes ii, caches; emits h1 f32 + bf16) -> h1
  k_spmm<1><<<256, 512, 0, stream>>>(bitsT, hWbP1, hWb1, oif, oib, colpart,
                                     ii_g, b1, out, h1b);
  // 3: oi * (h1@W2) panels (stages from bf16 h1b)
  k_hw2<<<256, 256, 0, stream>>>(h1b, W2TbP, oif, hWb2, hWbP2);
  // 4: layer-2 spmm (lean expansion, pre-scaled panels)
  k_spmm<0><<<256, 512, 0, stream>>>(bitsT, hWbP2, hWb2, oif, oib, colpart,
                                     ii_g, b2, out + (size_t)NN * DD, nullptr);
}